// Round 1
// baseline (3084.843 us; speedup 1.0000x reference)
//
#include <hip/hip_runtime.h>
#include <hip/hip_bf16.h>
#include <math.h>

// ---------------- problem constants ----------------
constexpr int B_   = 8;
constexpr int T_   = 128;
constexpr int D_   = 4;
constexpr int E_   = 1024;
constexpr int L_   = 2;
constexpr int V_   = 25000;
constexpr int CUT0_ = 2000;
constexpr int CUT1_ = 10000;
constexpr int HEAD_ = 2002;          // CUT0 + 2 clusters
constexpr int T0D_  = 256;           // E/4
constexpr int T1D_  = 64;            // E/16
constexpr int T0N_  = CUT1_ - CUT0_;  // 8000
constexpr int T1N_  = V_ - CUT1_;     // 15000
constexpr int NT_   = T_ - D_ + 1;    // 125
constexpr int NROW_ = B_ * NT_ * D_;  // 4000

__device__ __forceinline__ float sigm(float x) { return 1.0f / (1.0f + expf(-x)); }

// ---------------- embedding + prev build ----------------
// embedded[b,t,:] = emb[x[b,t]]
// prev[b,0,:]     = emb[x[b, lengths[b]-1]];  prev[b,j,:] = emb[x[b,j-1]]
__global__ __launch_bounds__(256) void embed_kernel(
    const int* __restrict__ x, const int* __restrict__ lengths,
    const float* __restrict__ emb,
    float* __restrict__ embedded, float* __restrict__ prev)
{
    int bt = blockIdx.x;
    int b = bt >> 7;          // /T_
    int t = bt & (T_ - 1);
    int tok  = x[bt];
    int ptok = (t == 0) ? x[b * T_ + lengths[b] - 1] : x[bt - 1];
    const float4* e0 = (const float4*)(emb + (size_t)tok  * E_);
    const float4* e1 = (const float4*)(emb + (size_t)ptok * E_);
    float4* d0 = (float4*)(embedded + (size_t)bt * E_);
    float4* d1 = (float4*)(prev     + (size_t)bt * E_);
    d0[threadIdx.x] = e0[threadIdx.x];   // E_/4 == 256 floats4 per row
    d1[threadIdx.x] = e1[threadIdx.x];
}

// ---------------- encoder mixing: wgt[b,t,e] = sum_s G[b,l,s,t] * f[b,s,e] ----------------
__global__ __launch_bounds__(256) void wgt_kernel(
    const float* __restrict__ G, const float* __restrict__ f,
    float* __restrict__ wgt, int l)
{
    __shared__ float gcol[T_];
    int bt = blockIdx.x;
    int b = bt >> 7;
    int t = bt & (T_ - 1);
    if (threadIdx.x < T_) {
        gcol[threadIdx.x] = G[((size_t)((b * L_ + l) * T_) + threadIdx.x) * T_ + t];
    }
    __syncthreads();
    const float* fb = f + (size_t)b * T_ * E_;
    for (int e = threadIdx.x; e < E_; e += 256) {
        float acc = 0.f;
        #pragma unroll 8
        for (int s = 0; s < T_; ++s) acc += gcol[s] * fb[(size_t)s * E_ + e];
        wgt[((size_t)bt) * E_ + e] = acc;
    }
}

// ---------------- generic NT GEMM: C[m,n] = sum_k A[m,k]*W[n,k] + bias[n] ----------------
// requires K % 16 == 0, lda/ldw % 4 == 0
#define TBM 64
#define TBN 64
#define TBK 16
__global__ __launch_bounds__(256) void gemm_nt_kernel(
    const float* __restrict__ A, int lda,
    const float* __restrict__ W, int ldw,
    const float* __restrict__ bias,
    float* __restrict__ C, int ldc,
    int M, int N, int K)
{
    __shared__ float As[TBK][TBM];
    __shared__ float Ws[TBK][TBN];
    int bm = blockIdx.y * TBM;
    int bn = blockIdx.x * TBN;
    int tid = threadIdx.x;
    int tx = tid & 15;    // col group
    int ty = tid >> 4;    // row group
    int lrow = tid >> 2;          // 0..63
    int lk4  = (tid & 3) << 2;    // 0,4,8,12

    float acc[4][4] = {};

    for (int k0 = 0; k0 < K; k0 += TBK) {
        // load A tile 64x16 (float4 per thread)
        {
            int gm = bm + lrow;
            float4 v = make_float4(0.f, 0.f, 0.f, 0.f);
            if (gm < M) v = *(const float4*)(A + (size_t)gm * lda + k0 + lk4);
            As[lk4 + 0][lrow] = v.x;
            As[lk4 + 1][lrow] = v.y;
            As[lk4 + 2][lrow] = v.z;
            As[lk4 + 3][lrow] = v.w;
            int gn = bn + lrow;
            float4 w = make_float4(0.f, 0.f, 0.f, 0.f);
            if (gn < N) w = *(const float4*)(W + (size_t)gn * ldw + k0 + lk4);
            Ws[lk4 + 0][lrow] = w.x;
            Ws[lk4 + 1][lrow] = w.y;
            Ws[lk4 + 2][lrow] = w.z;
            Ws[lk4 + 3][lrow] = w.w;
        }
        __syncthreads();
        #pragma unroll
        for (int kk = 0; kk < TBK; ++kk) {
            float4 av = *(const float4*)(&As[kk][ty * 4]);
            float4 wv = *(const float4*)(&Ws[kk][tx * 4]);
            float a[4] = {av.x, av.y, av.z, av.w};
            float w[4] = {wv.x, wv.y, wv.z, wv.w};
            #pragma unroll
            for (int i = 0; i < 4; ++i)
                #pragma unroll
                for (int j = 0; j < 4; ++j)
                    acc[i][j] += a[i] * w[j];
        }
        __syncthreads();
    }

    #pragma unroll
    for (int i = 0; i < 4; ++i) {
        int gm = bm + ty * 4 + i;
        if (gm >= M) continue;
        #pragma unroll
        for (int j = 0; j < 4; ++j) {
            int gn = bn + tx * 4 + j;
            if (gn < N) {
                float v = acc[i][j];
                if (bias) v += bias[gn];
                C[(size_t)gm * ldc + gn] = v;
            }
        }
    }
}

// ---------------- GRU gate ----------------
__global__ __launch_bounds__(256) void gru_gate_kernel(
    const float* __restrict__ gi, const float* __restrict__ gh,
    const float* __restrict__ hprev, float* __restrict__ hnew,
    float* __restrict__ outp, int ldout, int M)
{
    size_t idx = (size_t)blockIdx.x * 256 + threadIdx.x;
    if (idx >= (size_t)M * E_) return;
    int m = (int)(idx >> 10);        // /E_
    int e = (int)(idx & (E_ - 1));
    const float* gir = gi + (size_t)m * 3 * E_;
    const float* ghr = gh + (size_t)m * 3 * E_;
    float ir = gir[e], iz = gir[E_ + e], in_ = gir[2 * E_ + e];
    float hr = ghr[e], hz = ghr[E_ + e], hn  = ghr[2 * E_ + e];
    float r = sigm(ir + hr);
    float z = sigm(iz + hz);
    float n = tanhf(in_ + r * hn);
    float h = (1.0f - z) * n + z * hprev[(size_t)m * E_ + e];
    hnew[(size_t)m * E_ + e] = h;
    if (outp) outp[(size_t)m * ldout + e] = h;
}

// ---------------- row copy (h0 init / decoder window gather) ----------------
// dst[b*NT+t] = src[b*T + t + d]
__global__ __launch_bounds__(256) void copy_rows_kernel(
    const float* __restrict__ src, float* __restrict__ dst, int d)
{
    int m = blockIdx.x;             // b*NT + t
    int b = m / NT_;
    int t = m - b * NT_;
    const float4* s = (const float4*)(src + (size_t)(b * T_ + t + d) * E_);
    float4* dt = (float4*)(dst + (size_t)m * E_);
    dt[threadIdx.x] = s[threadIdx.x];
}

// ---------------- row-wise log-sum-exp ----------------
__global__ __launch_bounds__(256) void lse_kernel(
    const float* __restrict__ X, int ldx, int N, float* __restrict__ lse)
{
    int row = blockIdx.x;
    const float* xr = X + (size_t)row * ldx;
    float mx = -3.4e38f;
    for (int i = threadIdx.x; i < N; i += 256) mx = fmaxf(mx, xr[i]);
    __shared__ float sm[4];
    #pragma unroll
    for (int o = 32; o; o >>= 1) mx = fmaxf(mx, __shfl_down(mx, o));
    int w = threadIdx.x >> 6;
    if ((threadIdx.x & 63) == 0) sm[w] = mx;
    __syncthreads();
    mx = fmaxf(fmaxf(sm[0], sm[1]), fmaxf(sm[2], sm[3]));
    __syncthreads();
    float s = 0.f;
    for (int i = threadIdx.x; i < N; i += 256) s += expf(xr[i] - mx);
    #pragma unroll
    for (int o = 32; o; o >>= 1) s += __shfl_down(s, o);
    if ((threadIdx.x & 63) == 0) sm[w] = s;
    __syncthreads();
    if (threadIdx.x == 0) lse[row] = mx + logf(sm[0] + sm[1] + sm[2] + sm[3]);
}

// ---------------- finalize: log-softmax + cluster prior, write all V cols ----------------
__global__ __launch_bounds__(256) void finalize_kernel(
    const float* __restrict__ headlog, const float* __restrict__ lseH,
    const float* __restrict__ lse0, const float* __restrict__ lse1,
    float* __restrict__ out)
{
    size_t idx = (size_t)blockIdx.x * 256 + threadIdx.x;
    if (idx >= (size_t)NROW_ * V_) return;
    int row = (int)(idx / V_);
    int v = (int)(idx - (size_t)row * V_);
    float hl = lseH[row];
    if (v < CUT0_) {
        out[idx] = headlog[(size_t)row * HEAD_ + v] - hl;
    } else if (v < CUT1_) {
        float corr = headlog[(size_t)row * HEAD_ + CUT0_] - hl;
        out[idx] = out[idx] - lse0[row] + corr;
    } else {
        float corr = headlog[(size_t)row * HEAD_ + CUT0_ + 1] - hl;
        out[idx] = out[idx] - lse1[row] + corr;
    }
}

// ---------------- host side ----------------
static void launch_gemm(const float* A, int lda, const float* W, int ldw,
                        const float* bias, float* C, int ldc,
                        int M, int N, int K, hipStream_t stream)
{
    dim3 grid((N + TBN - 1) / TBN, (M + TBM - 1) / TBM);
    gemm_nt_kernel<<<grid, 256, 0, stream>>>(A, lda, W, ldw, bias, C, ldc, M, N, K);
}

extern "C" void kernel_launch(void* const* d_in, const int* in_sizes, int n_in,
                              void* d_out, int out_size, void* d_ws, size_t ws_size,
                              hipStream_t stream)
{
    const int*   x        = (const int*)d_in[0];
    const int*   lengths  = (const int*)d_in[1];
    const float* emb      = (const float*)d_in[2];
    const float* G        = (const float*)d_in[3];
    const float* enc_Wih  = (const float*)d_in[4];
    const float* enc_Whh  = (const float*)d_in[5];
    const float* enc_bih  = (const float*)d_in[6];
    const float* enc_bhh  = (const float*)d_in[7];
    const float* dec_Wih  = (const float*)d_in[8];
    const float* dec_Whh  = (const float*)d_in[9];
    const float* dec_bih  = (const float*)d_in[10];
    const float* dec_bhh  = (const float*)d_in[11];
    const float* head_W   = (const float*)d_in[12];
    const float* t0P      = (const float*)d_in[13];
    const float* t0W      = (const float*)d_in[14];
    const float* t1P      = (const float*)d_in[15];
    const float* t1W      = (const float*)d_in[16];
    float* out = (float*)d_out;

    // workspace carve-up (floats); total ~26.6M floats ~= 106 MB
    float* ws = (float*)d_ws;
    size_t off = 0;
    auto alloc = [&](size_t n) { float* p = ws + off; off += n; return p; };
    float* f0      = alloc((size_t)B_ * T_ * E_);      // embedded, then f after layer1
    float* prev    = alloc((size_t)B_ * T_ * E_);
    float* f1      = alloc((size_t)B_ * T_ * E_);
    float* wgt     = alloc((size_t)B_ * T_ * E_);
    float* gi      = alloc((size_t)B_ * T_ * 3 * E_);
    float* gh      = alloc((size_t)B_ * T_ * 3 * E_);
    float* h0      = alloc((size_t)B_ * NT_ * E_);
    float* h1      = alloc((size_t)B_ * NT_ * E_);
    float* xd      = alloc((size_t)B_ * NT_ * E_);
    float* H       = alloc((size_t)NROW_ * E_);        // decoder outputs, row = ((b*NT+t)*D+d)
    float* headlog = alloc((size_t)NROW_ * HEAD_);
    float* hp0     = alloc((size_t)NROW_ * T0D_);
    float* hp1     = alloc((size_t)NROW_ * T1D_);
    float* lseH    = alloc(NROW_);
    float* lse0    = alloc(NROW_);
    float* lse1    = alloc(NROW_);

    // 1) embedding + prev
    embed_kernel<<<B_ * T_, 256, 0, stream>>>(x, lengths, emb, f0, prev);

    // 2) encoder: two GRU layers with G-mixing
    const float* fin = f0;
    float* fout = f1;
    for (int l = 0; l < L_; ++l) {
        wgt_kernel<<<B_ * T_, 256, 0, stream>>>(G, fin, wgt, l);
        launch_gemm(wgt, E_, enc_Wih + (size_t)l * 3 * E_ * E_, E_,
                    enc_bih + (size_t)l * 3 * E_, gi, 3 * E_,
                    B_ * T_, 3 * E_, E_, stream);
        launch_gemm(fin, E_, enc_Whh + (size_t)l * 3 * E_ * E_, E_,
                    enc_bhh + (size_t)l * 3 * E_, gh, 3 * E_,
                    B_ * T_, 3 * E_, E_, stream);
        int tot = B_ * T_ * E_;
        gru_gate_kernel<<<(tot + 255) / 256, 256, 0, stream>>>(
            gi, gh, fin, fout, nullptr, 0, B_ * T_);
        const float* tmp = fin; fin = fout; fout = (float*)tmp;
    }

    // 3) decoder init: h = f[:, :NT]
    copy_rows_kernel<<<B_ * NT_, 256, 0, stream>>>(fin, h0, 0);

    // 4) decoder scan over D window positions
    float* hc = h0;
    float* hn = h1;
    for (int d = 0; d < D_; ++d) {
        copy_rows_kernel<<<B_ * NT_, 256, 0, stream>>>(prev, xd, d);
        launch_gemm(xd, E_, dec_Wih, E_, dec_bih, gi, 3 * E_,
                    B_ * NT_, 3 * E_, E_, stream);
        launch_gemm(hc, E_, dec_Whh, E_, dec_bhh, gh, 3 * E_,
                    B_ * NT_, 3 * E_, E_, stream);
        int tot = B_ * NT_ * E_;
        gru_gate_kernel<<<(tot + 255) / 256, 256, 0, stream>>>(
            gi, gh, hc, hn, H + (size_t)d * E_, D_ * E_, B_ * NT_);
        float* tmp = hc; hc = hn; hn = tmp;
    }

    // 5) adaptive softmax logits
    launch_gemm(H, E_, head_W, E_, nullptr, headlog, HEAD_, NROW_, HEAD_, E_, stream);
    launch_gemm(H, E_, t0P, E_, nullptr, hp0, T0D_, NROW_, T0D_, E_, stream);
    launch_gemm(hp0, T0D_, t0W, T0D_, nullptr, out + CUT0_, V_, NROW_, T0N_, T0D_, stream);
    launch_gemm(H, E_, t1P, E_, nullptr, hp1, T1D_, NROW_, T1D_, E_, stream);
    launch_gemm(hp1, T1D_, t1W, T1D_, nullptr, out + CUT1_, V_, NROW_, T1N_, T1D_, stream);

    // 6) row-wise log-sum-exp for the three softmaxes
    lse_kernel<<<NROW_, 256, 0, stream>>>(headlog, HEAD_, HEAD_, lseH);
    lse_kernel<<<NROW_, 256, 0, stream>>>(out + CUT0_, V_, T0N_, lse0);
    lse_kernel<<<NROW_, 256, 0, stream>>>(out + CUT1_, V_, T1N_, lse1);

    // 7) finalize all B*NT*D x V outputs
    size_t tot = (size_t)NROW_ * V_;
    finalize_kernel<<<(int)((tot + 255) / 256), 256, 0, stream>>>(
        headlog, lseH, lse0, lse1, out);
}